// Round 3
// baseline (142.728 us; speedup 1.0000x reference)
//
#include <hip/hip_runtime.h>
#include <hip/hip_cooperative_groups.h>

// RBFNN L1-distance, round 5: single cooperative fused kernel.
// Window decomposition (stable across r0-r2): ~40.5 us ws poison fill +
// ~35 us harness reset dispatches (fixed) + our kernels. r2 = 80.6 us with
// 2 dispatches. This round fuses k_out into k_sim via grid.sync():
//   - removes one dispatch gap (~1 us)
//   - removes the S round-trip: r2 wrote S (2MB), re-read (2MB), re-wrote
//     (2MB); now acc stays in registers across the barrier and d_out is
//     written once with final values (2MB total).
// Cooperative launch is harness-supported (guide §1); residency guaranteed:
// 1024 single-wave blocks, ~110 VGPR -> >=16 blocks/CU capacity >> 4 needed.
// k_sim body unchanged from r2 (known-good, ~5 us issue floor):
//   16x32 tile, 8 outputs/thread, per 64-k chunk: 12 f4 prefetched global
//   loads, 24 v_cvt_pkrtz, 6 ds_write_b128, 8 groups x 6 ds_read_b128
//   (imm offsets), v_pk_sub_f16 + v_and + v_dot2_f32_f16. No __syncthreads
//   (single-wave block, DS ordered by program order + lgkmcnt).

namespace cg = cooperative_groups;

typedef _Float16 h2 __attribute__((ext_vector_type(2)));
typedef float f4 __attribute__((ext_vector_type(4)));
typedef unsigned int u32;
typedef unsigned int u32x4 __attribute__((ext_vector_type(4)));

#define DIM_O 512
#define DIM_K 512
#define W_DIST 1.001f

__device__ __forceinline__ h2 as_h2(u32 u){ h2 r; __builtin_memcpy(&r,&u,4); return r; }
__device__ __forceinline__ u32 as_u(h2 h){ u32 r; __builtin_memcpy(&r,&h,4); return r; }
__device__ __forceinline__ u32 cvt2(float a, float b){
    auto h = __builtin_amdgcn_cvt_pkrtz(a, b);
    u32 r; __builtin_memcpy(&r, &h, 4); return r;
}

// LDS image (6144 B): X tile 16x64 f16 = 2048 B (2 slabs of 1024), C tile
// 32x64 f16 = 4096 B (4 slabs). Slab i, lane l holds 16 B at i*1024 + l*16.
//   X slab i, lane l = row (l&15), k = (l>>4)*8 + i*32 .. +8
//   C slab i, lane l = col (l&31), k = (l>>5)*8 + i*16 .. +8
// Read addressing (immediate offsets):
//   X row r, k-group g (8 f16): byte = (g>>2)*1024 + (g&3)*256 + r*16
//   C col c, k-group g        : byte = 2048 + (g>>1)*1024 + (g&1)*512 + c*16
__global__ __launch_bounds__(64) void k_fused(const float* __restrict__ X,
                                              const float* __restrict__ C,
                                              const float* __restrict__ beta,
                                              float* __restrict__ O,
                                              float* __restrict__ bmax)
{
    __shared__ __align__(16) char lds[6144];
    const int tid = threadIdx.x;
    const int bx = blockIdx.x & 15;   // 16 col tiles (512/32)
    const int by = blockIdx.x >> 4;   // 64 row tiles (1024/16)
    const int row0 = by * 16, col0 = bx * 32;
    const int tr = tid >> 4;          // 0..3 -> rows tr*4..tr*4+3
    const int tc = tid & 15;          // 0..15 -> cols tc, tc+16

    // per-lane f32 source bases matching the LDS image above
    const float* xsrc = X + (row0 + (tid & 15)) * DIM_K + (tid >> 4) * 8;
    const float* csrc = C + (col0 + (tid & 31)) * DIM_K + (tid >> 5) * 8;
    char* xdst = lds + tid * 16;          // + i*1024
    char* cdst = lds + 2048 + tid * 16;   // + i*1024

    f4 xv[4], cv[8];  // prefetch regs
    auto loadc = [&](int t) {
        const float* xq = xsrc + t * 64;
        const float* cq = csrc + t * 64;
#pragma unroll
        for (int i = 0; i < 2; ++i)
#pragma unroll
            for (int h = 0; h < 2; ++h)
                xv[2 * i + h] = *(const f4*)(xq + i * 32 + h * 4);
#pragma unroll
        for (int i = 0; i < 4; ++i)
#pragma unroll
            for (int h = 0; h < 2; ++h)
                cv[2 * i + h] = *(const f4*)(cq + i * 16 + h * 4);
    };

    float acc[4][2] = {};
    const h2 one2 = {(_Float16)1.f, (_Float16)1.f};

    loadc(0);

    for (int t = 0; t < 8; ++t) {
        // cvt + stage current chunk (consumes xv/cv -> frees them for prefetch)
#pragma unroll
        for (int i = 0; i < 2; ++i) {
            u32x4 w;
            w[0] = cvt2(xv[2 * i].x,     xv[2 * i].y);
            w[1] = cvt2(xv[2 * i].z,     xv[2 * i].w);
            w[2] = cvt2(xv[2 * i + 1].x, xv[2 * i + 1].y);
            w[3] = cvt2(xv[2 * i + 1].z, xv[2 * i + 1].w);
            *(u32x4*)(xdst + i * 1024) = w;
        }
#pragma unroll
        for (int i = 0; i < 4; ++i) {
            u32x4 w;
            w[0] = cvt2(cv[2 * i].x,     cv[2 * i].y);
            w[1] = cvt2(cv[2 * i].z,     cv[2 * i].w);
            w[2] = cvt2(cv[2 * i + 1].x, cv[2 * i + 1].y);
            w[3] = cvt2(cv[2 * i + 1].z, cv[2 * i + 1].w);
            *(u32x4*)(cdst + i * 1024) = w;
        }
        if (t < 7) loadc(t + 1);   // issue next chunk; flies under compute

        // compute: 8 groups of 8 k (4 h2) each; all reads b128, imm offsets
#pragma unroll
        for (int g = 0; g < 8; ++g) {
            const int xo = (g >> 2) * 1024 + (g & 3) * 256 + tr * 64;
            const int co = 2048 + (g >> 1) * 1024 + (g & 1) * 512 + tc * 16;
            u32x4 xr[4], cr[2];
            xr[0] = *(const u32x4*)(lds + xo);
            xr[1] = *(const u32x4*)(lds + xo + 16);
            xr[2] = *(const u32x4*)(lds + xo + 32);
            xr[3] = *(const u32x4*)(lds + xo + 48);
            cr[0] = *(const u32x4*)(lds + co);
            cr[1] = *(const u32x4*)(lds + co + 256);
#pragma unroll
            for (int k2 = 0; k2 < 4; ++k2) {
#pragma unroll
                for (int i = 0; i < 4; ++i) {
                    h2 a = as_h2(xr[i][k2]);
#pragma unroll
                    for (int j = 0; j < 2; ++j) {
                        h2 d = a - as_h2(cr[j][k2]);           // v_pk_sub_f16
                        h2 ad = as_h2(as_u(d) & 0x7fff7fffu);  // abs both halves
                        acc[i][j] = __builtin_amdgcn_fdot2(ad, one2, acc[i][j], false);
                    }
                }
            }
        }
    }

    // block max -> bmax[bid]
    float m = 0.f;
#pragma unroll
    for (int i = 0; i < 4; ++i)
        m = fmaxf(m, fmaxf(acc[i][0], acc[i][1]));
#pragma unroll
    for (int off = 32; off > 0; off >>= 1)
        m = fmaxf(m, __shfl_xor(m, off, 64));
    if (tid == 0) bmax[blockIdx.x] = m;

    // prefetch beta while other blocks finish
    const float b0 = beta[col0 + tc];
    const float b1 = beta[col0 + tc + 16];

    __threadfence();
    cg::this_grid().sync();

    // global max: every block redundantly reduces the 1024 entries (L2-hot)
    float gm = 0.f;
#pragma unroll
    for (int i = 0; i < 16; ++i)
        gm = fmaxf(gm, bmax[tid + 64 * i]);
#pragma unroll
    for (int off = 32; off > 0; off >>= 1)
        gm = fmaxf(gm, __shfl_xor(gm, off, 64));
    const float shift = gm * W_DIST;

    // final output straight from registers: O written exactly once
#pragma unroll
    for (int i = 0; i < 4; ++i) {
        const int r = row0 + tr * 4 + i;
        O[r * DIM_O + col0 + tc]      = b0 * (shift - acc[i][0]);
        O[r * DIM_O + col0 + tc + 16] = b1 * (shift - acc[i][1]);
    }
}

extern "C" void kernel_launch(void* const* d_in, const int* in_sizes, int n_in,
                              void* d_out, int out_size, void* d_ws, size_t ws_size,
                              hipStream_t stream) {
    const float* X = (const float*)d_in[0];
    const float* C = (const float*)d_in[1];
    const float* beta = (const float*)d_in[2];
    float* O = (float*)d_out;
    float* bmax = (float*)d_ws;   // 1024 floats scratch
    void* args[] = {(void*)&X, (void*)&C, (void*)&beta, (void*)&O, (void*)&bmax};
    hipLaunchCooperativeKernel((void*)k_fused, dim3(1024), dim3(64), args, 0, stream);
}

// Round 4
// 80.184 us; speedup vs baseline: 1.7800x; 1.7800x over previous
//
#include <hip/hip_runtime.h>

// RBFNN L1-distance, round 6: REVERT to round-4/r2 two-dispatch pipeline
// (session-best 80.6 us). Round-5 post-mortem: cooperative grid.sync() on a
// 1024-block grid costs ~65 us on gfx950 (k_fused 71 us, VALUBusy 14%, HBM 2%
// -> pure spin; FETCH +5.8 MB from cross-XCD barrier/bmax coherence traffic).
// Grid-wide sync latency >> dispatch-gap latency here; fusion is net -62 us.
// Window decomposition (stable r0-r2): ~40.5 us ws poison fill + ~35 us
// harness reset dispatches (fixed) + ~5-6 us our kernels (controllable).
// k_sim: 1024 blocks x 64 threads (single wave). Tile 16x32, 8 outputs/thread
//   (rows tr*4..+3, cols {tc, tc+16}). Per chunk (64 k): 12 f4 global loads
//   (prefetched 1 chunk ahead, fly under the 1536-cycle compute), 24
//   v_cvt_pkrtz f32->f16x2, 6 ds_write_b128 (2-way banked = free), then
//   8 groups x 6 ds_read_b128 (imm offsets) feeding v_pk_sub_f16 + v_and(abs)
//   + v_dot2_f32_f16 (1.5 instr/pair, f32 accum) — ~5.1 us VALU issue floor;
//   no MFMA mapping exists for L1 distance. No __syncthreads (single-wave
//   block: DS ops wave-ordered, compiler inserts lgkmcnt).
// k_out: reduce 1024 block maxes in-wave, out = beta*(max*1.001 - sim).

typedef _Float16 h2 __attribute__((ext_vector_type(2)));
typedef float f4 __attribute__((ext_vector_type(4)));
typedef unsigned int u32;
typedef unsigned int u32x4 __attribute__((ext_vector_type(4)));

#define DIM_O 512
#define DIM_K 512
#define W_DIST 1.001f

__device__ __forceinline__ h2 as_h2(u32 u){ h2 r; __builtin_memcpy(&r,&u,4); return r; }
__device__ __forceinline__ u32 as_u(h2 h){ u32 r; __builtin_memcpy(&r,&h,4); return r; }
__device__ __forceinline__ u32 cvt2(float a, float b){
    auto h = __builtin_amdgcn_cvt_pkrtz(a, b);
    u32 r; __builtin_memcpy(&r, &h, 4); return r;
}

// ---------------- k_sim ----------------
// LDS image (6144 B): X tile 16x64 f16 = 2048 B (2 slabs of 1024), C tile
// 32x64 f16 = 4096 B (4 slabs). Slab i, lane l holds 16 B at i*1024 + l*16.
//   X slab i, lane l = row (l&15), k = (l>>4)*8 + i*32 .. +8
//   C slab i, lane l = col (l&31), k = (l>>5)*8 + i*16 .. +8
// Read addressing (immediate offsets):
//   X row r, k-group g (8 f16): byte = (g>>2)*1024 + (g&3)*256 + r*16
//   C col c, k-group g        : byte = 2048 + (g>>1)*1024 + (g&1)*512 + c*16
__global__ __launch_bounds__(64) void k_sim(const float* __restrict__ X,
                                            const float* __restrict__ C,
                                            float* __restrict__ S,
                                            float* __restrict__ bmax)
{
    __shared__ __align__(16) char lds[6144];
    const int tid = threadIdx.x;
    const int bx = blockIdx.x & 15;   // 16 col tiles (512/32)
    const int by = blockIdx.x >> 4;   // 64 row tiles (1024/16)
    const int row0 = by * 16, col0 = bx * 32;
    const int tr = tid >> 4;          // 0..3 -> rows tr*4..tr*4+3
    const int tc = tid & 15;          // 0..15 -> cols tc, tc+16

    // per-lane f32 source bases matching the LDS image above
    const float* xsrc = X + (row0 + (tid & 15)) * DIM_K + (tid >> 4) * 8;
    const float* csrc = C + (col0 + (tid & 31)) * DIM_K + (tid >> 5) * 8;
    char* xdst = lds + tid * 16;          // + i*1024
    char* cdst = lds + 2048 + tid * 16;   // + i*1024

    f4 xv[4], cv[8];  // prefetch regs: xv[2i+h] = floats (l>>4)*8 + i*32 + h*4..
    auto loadc = [&](int t) {
        const float* xq = xsrc + t * 64;
        const float* cq = csrc + t * 64;
#pragma unroll
        for (int i = 0; i < 2; ++i)
#pragma unroll
            for (int h = 0; h < 2; ++h)
                xv[2 * i + h] = *(const f4*)(xq + i * 32 + h * 4);
#pragma unroll
        for (int i = 0; i < 4; ++i)
#pragma unroll
            for (int h = 0; h < 2; ++h)
                cv[2 * i + h] = *(const f4*)(cq + i * 16 + h * 4);
    };

    float acc[4][2] = {};
    const h2 one2 = {(_Float16)1.f, (_Float16)1.f};

    loadc(0);

    for (int t = 0; t < 8; ++t) {
        // cvt + stage current chunk (consumes xv/cv -> frees them for prefetch)
#pragma unroll
        for (int i = 0; i < 2; ++i) {
            u32x4 w;
            w[0] = cvt2(xv[2 * i].x,     xv[2 * i].y);
            w[1] = cvt2(xv[2 * i].z,     xv[2 * i].w);
            w[2] = cvt2(xv[2 * i + 1].x, xv[2 * i + 1].y);
            w[3] = cvt2(xv[2 * i + 1].z, xv[2 * i + 1].w);
            *(u32x4*)(xdst + i * 1024) = w;
        }
#pragma unroll
        for (int i = 0; i < 4; ++i) {
            u32x4 w;
            w[0] = cvt2(cv[2 * i].x,     cv[2 * i].y);
            w[1] = cvt2(cv[2 * i].z,     cv[2 * i].w);
            w[2] = cvt2(cv[2 * i + 1].x, cv[2 * i + 1].y);
            w[3] = cvt2(cv[2 * i + 1].z, cv[2 * i + 1].w);
            *(u32x4*)(cdst + i * 1024) = w;
        }
        if (t < 7) loadc(t + 1);   // issue next chunk; flies under compute

        // compute: 8 groups of 8 k (4 h2) each; all reads b128, imm offsets
#pragma unroll
        for (int g = 0; g < 8; ++g) {
            const int xo = (g >> 2) * 1024 + (g & 3) * 256 + tr * 64;
            const int co = 2048 + (g >> 1) * 1024 + (g & 1) * 512 + tc * 16;
            u32x4 xr[4], cr[2];
            xr[0] = *(const u32x4*)(lds + xo);
            xr[1] = *(const u32x4*)(lds + xo + 16);
            xr[2] = *(const u32x4*)(lds + xo + 32);
            xr[3] = *(const u32x4*)(lds + xo + 48);
            cr[0] = *(const u32x4*)(lds + co);
            cr[1] = *(const u32x4*)(lds + co + 256);
#pragma unroll
            for (int k2 = 0; k2 < 4; ++k2) {
#pragma unroll
                for (int i = 0; i < 4; ++i) {
                    h2 a = as_h2(xr[i][k2]);
#pragma unroll
                    for (int j = 0; j < 2; ++j) {
                        h2 d = a - as_h2(cr[j][k2]);           // v_pk_sub_f16
                        h2 ad = as_h2(as_u(d) & 0x7fff7fffu);  // abs both halves
                        acc[i][j] = __builtin_amdgcn_fdot2(ad, one2, acc[i][j], false);
                    }
                }
            }
        }
    }

    // epilogue: store sim + block max
    float m = 0.f;
#pragma unroll
    for (int i = 0; i < 4; ++i) {
        const int r = row0 + tr * 4 + i;
        S[r * DIM_O + col0 + tc]      = acc[i][0];
        S[r * DIM_O + col0 + tc + 16] = acc[i][1];
        m = fmaxf(m, fmaxf(acc[i][0], acc[i][1]));
    }
#pragma unroll
    for (int off = 32; off > 0; off >>= 1)
        m = fmaxf(m, __shfl_xor(m, off, 64));
    if (tid == 0) bmax[blockIdx.x] = m;
}

// ---------------- k_out ----------------
__global__ __launch_bounds__(256) void k_out(float* __restrict__ S,
                                             const float* __restrict__ beta,
                                             const float* __restrict__ bmax)
{
    const int tid = threadIdx.x;
    const int lane = tid & 63;
    float m = 0.f;
#pragma unroll
    for (int i = 0; i < 16; ++i) // 1024 block maxes
        m = fmaxf(m, bmax[lane + 64 * i]);
#pragma unroll
    for (int off = 32; off > 0; off >>= 1)
        m = fmaxf(m, __shfl_xor(m, off, 64));
    const float shift = m * W_DIST;

    const int f = blockIdx.x * 256 + tid; // float4 index, 131072 total
    f4 s = ((const f4*)S)[f];
    f4 b = ((const f4*)beta)[f & 127];
    f4 r;
    r.x = b.x * (shift - s.x);
    r.y = b.y * (shift - s.y);
    r.z = b.z * (shift - s.z);
    r.w = b.w * (shift - s.w);
    ((f4*)S)[f] = r;
}

extern "C" void kernel_launch(void* const* d_in, const int* in_sizes, int n_in,
                              void* d_out, int out_size, void* d_ws, size_t ws_size,
                              hipStream_t stream) {
    const float* X = (const float*)d_in[0];
    const float* C = (const float*)d_in[1];
    const float* beta = (const float*)d_in[2];
    float* S = (float*)d_out;     // sim staged in d_out, transformed in place
    float* bmax = (float*)d_ws;   // 1024 floats scratch
    k_sim<<<1024, 64, 0, stream>>>(X, C, S, bmax);
    k_out<<<512, 256, 0, stream>>>(S, beta, bmax);
}